// Round 7
// baseline (226.739 us; speedup 1.0000x reference)
//
#include <hip/hip_runtime.h>
#include <cstdint>

// Problem constants (fixed by reference)
#define NB      8
#define NN      4096
#define NCLS    80
#define MAXDET  300

// Output float layout (flat, 16808 elements)
#define OFF_IDX  0
#define OFF_SCR  2400
#define OFF_BOX  4800
#define OFF_CLS  14400
#define OFF_NDT  16800

// IoU > thr test, matching reference arithmetic exactly (no FMA contraction).
__device__ __forceinline__ bool iou_gt(float c0, float c1, float c2, float c3,
                                       float t0, float t1, float t2, float t3,
                                       float tarea)
{
#pragma clang fp contract(off)
    float xx1 = fmaxf(c0, t0);
    float yy1 = fmaxf(c1, t1);
    float xx2 = fminf(c2, t2);
    float yy2 = fminf(c3, t3);
    float w = xx2 - xx1; w = fmaxf(w, 0.0f);
    float h = yy2 - yy1; h = fmaxf(h, 0.0f);
    float inter = w * h;
    float areac = (c2 - c0) * (c3 - c1);
    float uni = areac + tarea - inter;
    return (inter / uni) > 0.65f;
}

__device__ __forceinline__ uint64_t shfl_xor64(uint64_t x, int m)
{
    unsigned lo = __shfl_xor((unsigned)x, m, 64);
    unsigned hi = __shfl_xor((unsigned)(x >> 32), m, 64);
    return ((uint64_t)hi << 32) | lo;
}

__device__ __forceinline__ void ce64(uint64_t& a, uint64_t& b, bool desc)
{
    uint64_t lo = (a < b) ? a : b;
    uint64_t hi = (a < b) ? b : a;
    a = desc ? hi : lo;
    b = desc ? lo : hi;
}

// =================== one block per batch; zero inter-block traffic ===================
// 8 blocks x 512 threads (8 waves). Rounds 5/6 used 1024-thread blocks: the
// toolchain capped them at 64 VGPRs (observed with AND without min-waves arg),
// below the NMS loop's ~80-100 peak -> ~320 B/thread scratch spill (WRITE_SIZE
// 2.5 MB) -> latency-bound 150 us. At 512 threads the cap is >=128; spill gone.
//   scan:   stage scores (f32) + validity-encoded class bytes into LDS.
//   NMS:    wave wv owns classes {wv, wv+8, ..., wv+72}: ballot compaction ->
//           in-wave bitonic (64/128) -> IoU + serial-ballot suppress ->
//           survivor bitmask + fused score histogram.
//   select: exact-bin cutoff -> gather <=512 candidates -> 256-thread x 4-elem
//           1024-key bitonic -> pack.
// No workspace, no fences, no global atomics, no memset dispatch.
__global__ __launch_bounds__(512, 1)
void k_nms_batch(const float* __restrict__ scores,
                 const float* __restrict__ boxes,
                 const int*   __restrict__ classes,
                 float* __restrict__ out)
{
    const int b    = blockIdx.x;
    const int tid  = threadIdx.x;
    const int lane = tid & 63;
    const int wv   = tid >> 6;           // 0..7
    const int bN   = b * NN;
    const uint64_t lmask = (1ull << lane) - 1ull;

    __shared__ alignas(16) float         score_s[NN];        // 16 KB
    __shared__ alignas(16) unsigned char cls8[NN];           //  4 KB (0xFF = invalid)
    __shared__ alignas(16) uint64_t      wscr[8 * 160];      // 10 KB: per-wave scratch
    __shared__ int      hist[256];                           //  1 KB
    __shared__ uint64_t cand[1024];                          //  8 KB
    __shared__ unsigned aliveE[NN / 32];                     //  0.5 KB survivor bitmask
    __shared__ int      keptn_s, ncand_s, cutoff_s;

    // ---- init + static output fills (out poisoned each replay) ----
    if (tid < NN / 32) aliveE[tid] = 0u;
    if (tid < 256) hist[tid] = 0;
    if (tid == 0) { keptn_s = 0; ncand_s = 0; cutoff_s = 256; }
    if (tid < MAXDET) {
        out[OFF_IDX + b * MAXDET + tid] = -1.0f;
        out[OFF_SCR + b * MAXDET + tid] = 0.0f;
        int ob = OFF_BOX + (b * MAXDET + tid) * 4;
        out[ob + 0] = 0.0f; out[ob + 1] = 0.0f;
        out[ob + 2] = 0.0f; out[ob + 3] = 0.0f;
        out[OFF_CLS + b * MAXDET + tid] = 0.0f;
    }

    // ---- scan: thread t stages elements 8t..8t+7 (two float4/int4 each) ----
    {
#pragma unroll
        for (int h = 0; h < 2; ++h) {
            const int vi = (tid << 1) | h;
            const float4 sv = ((const float4*)(scores + bN))[vi];
            const int4   cv = ((const int4*)(classes + bN))[vi];
            ((float4*)score_s)[vi] = sv;
            unsigned p0 = (sv.x > 0.05f) ? (unsigned)cv.x : 0xFFu;
            unsigned p1 = (sv.y > 0.05f) ? (unsigned)cv.y : 0xFFu;
            unsigned p2 = (sv.z > 0.05f) ? (unsigned)cv.z : 0xFFu;
            unsigned p3 = (sv.w > 0.05f) ? (unsigned)cv.w : 0xFFu;
            ((unsigned*)cls8)[vi] = p0 | (p1 << 8) | (p2 << 16) | (p3 << 24);
        }
    }
    __syncthreads();

    // ---- per-class NMS: wave wv owns classes wv + 8q, q in [0,10) ----
    uint64_t* wk  = &wscr[wv * 160];          // [0..127] compact keys (u64)
    float4*   wbx = (float4*)wk;              // overlay: staged boxes (fast path)
    float*    war = (float*)(wk + 128);       // staged areas
    const float4*   boxes4 = (const float4*)boxes;
    const unsigned* clsu   = (const unsigned*)cls8;

    for (int q = 0; q < 10; ++q) {
        const unsigned c = (unsigned)(wv + (q << 3));

        // ballot compaction: 16 iters x 256 elements (4 bytes/lane)
        int cnt = 0;
        for (int it = 0; it < 16; ++it) {
            const unsigned d = clsu[(it << 6) | lane];
            const bool m0 = ((d      ) & 0xFFu) == c;
            const bool m1 = ((d >>  8) & 0xFFu) == c;
            const bool m2 = ((d >> 16) & 0xFFu) == c;
            const bool m3 = ( d >> 24        ) == c;
            const uint64_t B0 = __ballot(m0), B1 = __ballot(m1);
            const uint64_t B2 = __ballot(m2), B3 = __ballot(m3);
            int r = cnt + __popcll(B0 & lmask) + __popcll(B1 & lmask)
                        + __popcll(B2 & lmask) + __popcll(B3 & lmask);
            const int e0 = ((it << 6) | lane) << 2;
            if (m0) { if (r < 128) wk[r] = (((uint64_t)(__float_as_uint(score_s[e0 + 0]) | 0x80000000u)) << 32) | (unsigned)(e0 + 0); ++r; }
            if (m1) { if (r < 128) wk[r] = (((uint64_t)(__float_as_uint(score_s[e0 + 1]) | 0x80000000u)) << 32) | (unsigned)(e0 + 1); ++r; }
            if (m2) { if (r < 128) wk[r] = (((uint64_t)(__float_as_uint(score_s[e0 + 2]) | 0x80000000u)) << 32) | (unsigned)(e0 + 2); ++r; }
            if (m3) { if (r < 128) wk[r] = (((uint64_t)(__float_as_uint(score_s[e0 + 3]) | 0x80000000u)) << 32) | (unsigned)(e0 + 3); ++r; }
            cnt += __popcll(B0) + __popcll(B1) + __popcll(B2) + __popcll(B3);
        }
        const int nc = cnt > 128 ? 128 : cnt;
        if (nc <= 0) continue;

        if (nc <= 64) {
            // ---- fast path: in-wave descending bitonic of 64 keys ----
            uint64_t key = (lane < nc) ? wk[lane] : 0ull;
            for (int k = 2; k <= 64; k <<= 1) {
                bool up = ((lane & k) == 0);
                for (int j = k >> 1; j >= 1; j >>= 1) {
                    uint64_t w = shfl_xor64(key, j);
                    bool km = (((lane & j) == 0) == up);
                    key = km ? (key > w ? key : w) : (key < w ? key : w);
                }
            }
            const unsigned idx = (unsigned)key;
            float4 bx = make_float4(0, 0, 0, 0);
            float  area = 0.0f;
            if (lane < nc) {
                bx = boxes4[bN + idx];
                {
#pragma clang fp contract(off)
                    area = (bx.z - bx.x) * (bx.w - bx.y);
                }
            }
            wbx[lane] = bx;              // keys already in regs; scratch reuse OK
            war[lane] = area;
            uint64_t ov = 0;
            for (int j0 = 0; j0 < nc - 1; j0 += 4) {
                float4 t[4]; float ta[4];
#pragma unroll
                for (int r = 0; r < 4; ++r) { t[r] = wbx[j0 + r]; ta[r] = war[j0 + r]; }
#pragma unroll
                for (int r = 0; r < 4; ++r) {
                    int j = j0 + r;
                    if (j < nc - 1 && lane > j && lane < nc &&
                        iou_gt(bx.x, bx.y, bx.z, bx.w,
                               t[r].x, t[r].y, t[r].z, t[r].w, ta[r]))
                        ov |= 1ull << j;
                }
            }
            uint64_t alive = (nc >= 64) ? ~0ull : ((1ull << nc) - 1ull);
            for (int t = 0; t < nc; ++t) {
                if (!((alive >> t) & 1ull)) continue;
                uint64_t die = __ballot(((ov >> t) & 1ull) != 0);
                alive &= ~die;
            }
            if (lane == 0) atomicAdd(&keptn_s, __popcll(alive));
            if (lane < nc && ((alive >> lane) & 1ull)) {
                unsigned e = (unsigned)key;
                atomicOr(&aliveE[e >> 5], 1u << (e & 31));
                float f = __uint_as_float((unsigned)(key >> 32) & 0x7FFFFFFFu);
                int bin = (int)(f * 256.0f); bin = bin > 255 ? 255 : bin;
                atomicAdd(&hist[bin], 1);
            }
        } else {
            // ---- medium path (rare, nc in 65..128): 2-reg bitonic + shfl IoU ----
            const int mB = 64 + lane;
            uint64_t kA = (lane < nc) ? wk[lane] : 0ull;
            uint64_t kB = (mB < nc) ? wk[mB] : 0ull;
            for (int k = 2; k <= 128; k <<= 1) {
                bool up0 = ((lane & k) == 0);
                bool up1 = ((mB & k) == 0);
                for (int j = k >> 1; j >= 1; j >>= 1) {
                    if (j == 64) {
                        ce64(kA, kB, up0);   // k==128 here: up0 == true
                    } else {
                        uint64_t wA = shfl_xor64(kA, j);
                        uint64_t wB = shfl_xor64(kB, j);
                        bool kmA = (((lane & j) == 0) == up0);
                        bool kmB = (((lane & j) == 0) == up1);
                        kA = kmA ? (kA > wA ? kA : wA) : (kA < wA ? kA : wA);
                        kB = kmB ? (kB > wB ? kB : wB) : (kB < wB ? kB : wB);
                    }
                }
            }
            const unsigned idxA = (unsigned)kA, idxB = (unsigned)kB;
            float4 bA = make_float4(0, 0, 0, 0), bB = bA;
            float  aA = 0.0f, aB = 0.0f;
            if (lane < nc) {
                bA = boxes4[bN + idxA];
                {
#pragma clang fp contract(off)
                    aA = (bA.z - bA.x) * (bA.w - bA.y);
                }
            }
            if (mB < nc) {
                bB = boxes4[bN + idxB];
                {
#pragma clang fp contract(off)
                    aB = (bB.z - bB.x) * (bB.w - bB.y);
                }
            }
            uint64_t ovA0 = 0, ovB0 = 0, ovB1 = 0;
            for (int j = 0; j < nc - 1; ++j) {
                float t0, t1, t2, t3, ta;
                if (j < 64) {
                    t0 = __shfl(bA.x, j, 64); t1 = __shfl(bA.y, j, 64);
                    t2 = __shfl(bA.z, j, 64); t3 = __shfl(bA.w, j, 64);
                    ta = __shfl(aA, j, 64);
                    if (lane > j && lane < nc &&
                        iou_gt(bA.x, bA.y, bA.z, bA.w, t0, t1, t2, t3, ta))
                        ovA0 |= 1ull << j;
                    if (mB < nc &&
                        iou_gt(bB.x, bB.y, bB.z, bB.w, t0, t1, t2, t3, ta))
                        ovB0 |= 1ull << j;
                } else {
                    int js = j - 64;
                    t0 = __shfl(bB.x, js, 64); t1 = __shfl(bB.y, js, 64);
                    t2 = __shfl(bB.z, js, 64); t3 = __shfl(bB.w, js, 64);
                    ta = __shfl(aB, js, 64);
                    if (mB > j && mB < nc &&
                        iou_gt(bB.x, bB.y, bB.z, bB.w, t0, t1, t2, t3, ta))
                        ovB1 |= 1ull << js;
                }
            }
            uint64_t alive0 = (nc >= 64) ? ~0ull : ((1ull << nc) - 1ull);
            uint64_t alive1 = (nc >= 128) ? ~0ull : ((1ull << (nc - 64)) - 1ull);
            for (int t = 0; t < nc; ++t) {
                if (t < 64) {
                    if (!((alive0 >> t) & 1ull)) continue;
                    uint64_t d0 = __ballot(((ovA0 >> t) & 1ull) != 0);
                    uint64_t d1 = __ballot(((ovB0 >> t) & 1ull) != 0);
                    alive0 &= ~d0;
                    alive1 &= ~d1;
                } else {
                    int tt = t - 64;
                    if (!((alive1 >> tt) & 1ull)) continue;
                    uint64_t d1 = __ballot(((ovB1 >> tt) & 1ull) != 0);
                    alive1 &= ~d1;
                }
            }
            if (lane == 0) atomicAdd(&keptn_s, __popcll(alive0) + __popcll(alive1));
            if (lane < nc && ((alive0 >> lane) & 1ull)) {
                unsigned e = (unsigned)kA;
                atomicOr(&aliveE[e >> 5], 1u << (e & 31));
                float f = __uint_as_float((unsigned)(kA >> 32) & 0x7FFFFFFFu);
                int bin = (int)(f * 256.0f); bin = bin > 255 ? 255 : bin;
                atomicAdd(&hist[bin], 1);
            }
            if (mB < nc && ((alive1 >> lane) & 1ull)) {
                unsigned e = (unsigned)kB;
                atomicOr(&aliveE[e >> 5], 1u << (e & 31));
                float f = __uint_as_float((unsigned)(kB >> 32) & 0x7FFFFFFFu);
                int bin = (int)(f * 256.0f); bin = bin > 255 ? 255 : bin;
                atomicAdd(&hist[bin], 1);
            }
        }
    }
    __syncthreads();

    // ---- cutoff: exact 1-bin granularity (wave 0) ----
    const int kept_n = keptn_s;
    const int target = kept_n < MAXDET ? kept_n : MAXDET;
    if (tid == 0) out[OFF_NDT + b] = (float)target;
    if (wv == 0) {
        int h0 = hist[4 * lane + 0], h1 = hist[4 * lane + 1];
        int h2 = hist[4 * lane + 2], h3 = hist[4 * lane + 3];
        int s = h0 + h1 + h2 + h3;
#pragma unroll
        for (int off = 1; off < 64; off <<= 1) {
            int t = __shfl_down(s, off, 64);
            if (lane + off < 64) s += t;
        }
        int snext = __shfl_down(s, 1, 64);
        if (lane == 63) snext = 0;
        int u0 = s;            // suffix(4L)
        int u1 = u0 - h0;      // suffix(4L+1)
        int u2 = u1 - h1;      // suffix(4L+2)
        int u3 = u2 - h2;      // suffix(4L+3)
        int u4 = snext;        // suffix(4L+4)
        if (target > 0) {
            if (u0 >= target && u1 < target) cutoff_s = 4 * lane + 0;
            if (u1 >= target && u2 < target) cutoff_s = 4 * lane + 1;
            if (u2 >= target && u3 < target) cutoff_s = 4 * lane + 2;
            if (u3 >= target && u4 < target) cutoff_s = 4 * lane + 3;
        }
    }
    __syncthreads();
    const int cutoff = cutoff_s;

    // ---- gather candidates from survivor bitmask (512 threads x 8 elems) ----
#pragma unroll
    for (int k2 = 0; k2 < 8; ++k2) {
        const int e = (tid << 3) | k2;
        if ((aliveE[e >> 5] >> (e & 31)) & 1u) {
            float f = score_s[e];
            int bin = (int)(f * 256.0f); bin = bin > 255 ? 255 : bin;
            if (bin >= cutoff) {
                int slot = atomicAdd(&ncand_s, 1);
                if (slot < 512)
                    cand[slot] = (((uint64_t)(__float_as_uint(f) | 0x80000000u)) << 32) | (unsigned)e;
            }
        }
    }
    __syncthreads();
    const int ncand = ncand_s < 512 ? ncand_s : 512;
    for (int i = tid; i < 1024; i += 512)
        if (i >= ncand) cand[i] = 0ull;      // zero-pad slots ncand..1023
    __syncthreads();

    // ---- descending bitonic sort of 1024 u64 keys (256 thr x 4 elems) ----
    // Waves 4..7 idle but execute the barriers (loop bounds compile-time ->
    // block-uniform control flow).
    // i bits: [1:0]=e (register), [7:2]=lane (shfl), [9:8]=wave (LDS)
    const int base = tid << 2;
    uint64_t v[4] = {0ull, 0ull, 0ull, 0ull};
    if (wv < 4) {
#pragma unroll
        for (int e = 0; e < 4; ++e) v[e] = cand[base + e];
    }
    for (int k = 2; k <= 1024; k <<= 1) {
        for (int j = k >> 1; j >= 1; j >>= 1) {
            if (j >= 256) {
                __syncthreads();
                if (wv < 4) {
#pragma unroll
                    for (int e = 0; e < 4; ++e) cand[base + e] = v[e];
                }
                __syncthreads();
                if (wv < 4) {
                    const int pb = base ^ j;
                    const bool keepmax = (((base & j) == 0) == ((base & k) == 0));
                    uint64_t w[4];
#pragma unroll
                    for (int e = 0; e < 4; ++e) w[e] = cand[pb + e];
#pragma unroll
                    for (int e = 0; e < 4; ++e) {
                        uint64_t a = v[e], cc = w[e];
                        v[e] = keepmax ? (a > cc ? a : cc) : (a < cc ? a : cc);
                    }
                }
            } else if (j >= 4) {
                if (wv < 4) {
                    const int m = j >> 2;
                    const bool keepmax = (((lane & m) == 0) == ((base & k) == 0));
                    unsigned wlo[4], whi[4];
#pragma unroll
                    for (int e = 0; e < 4; ++e) wlo[e] = __shfl_xor((unsigned)v[e], m, 64);
#pragma unroll
                    for (int e = 0; e < 4; ++e) whi[e] = __shfl_xor((unsigned)(v[e] >> 32), m, 64);
#pragma unroll
                    for (int e = 0; e < 4; ++e) {
                        uint64_t w = ((uint64_t)whi[e] << 32) | wlo[e];
                        uint64_t a = v[e];
                        v[e] = keepmax ? (a > w ? a : w) : (a < w ? a : w);
                    }
                }
            } else if (j == 2) {
                if (wv < 4) {
                    bool d = ((base & k) == 0);
                    ce64(v[0], v[2], d);
                    ce64(v[1], v[3], d);
                }
            } else {
                if (wv < 4) {
                    bool d0 = (((base + 0) & k) == 0);
                    bool d2 = (((base + 2) & k) == 0);
                    ce64(v[0], v[1], d0);
                    ce64(v[2], v[3], d2);
                }
            }
        }
    }

    // ---- pack top-target detections (rank = sorted position) ----
    if (wv < 4) {
#pragma unroll
        for (int e = 0; e < 4; ++e) {
            const int rank = base + e;
            if (rank < target) {
                const uint64_t kv = v[e];
                const unsigned idx = (unsigned)kv;
                out[OFF_SCR + b * MAXDET + rank] = __uint_as_float((unsigned)(kv >> 32) & 0x7FFFFFFFu);
                float4 g = boxes4[bN + idx];
                int ob = OFF_BOX + (b * MAXDET + rank) * 4;
                out[ob + 0] = g.x; out[ob + 1] = g.y;
                out[ob + 2] = g.z; out[ob + 3] = g.w;
                out[OFF_CLS + b * MAXDET + rank] = (float)cls8[idx];
            }
        }
    }
}

extern "C" void kernel_launch(void* const* d_in, const int* in_sizes, int n_in,
                              void* d_out, int out_size, void* d_ws, size_t ws_size,
                              hipStream_t stream)
{
    const float* scores  = (const float*)d_in[0];
    const float* boxes   = (const float*)d_in[1];
    const int*   classes = (const int*)d_in[2];
    float*       out     = (float*)d_out;

    hipLaunchKernelGGL(k_nms_batch, dim3(NB), dim3(512), 0, stream,
                       scores, boxes, classes, out);
}

// Round 8
// 173.380 us; speedup vs baseline: 1.3078x; 1.3078x over previous
//
#include <hip/hip_runtime.h>
#include <cstdint>

// Problem constants (fixed by reference)
#define NB      8
#define NN      4096
#define NCLS    80
#define MAXDET  300
#define NTHR    768          // 12 waves

// Output float layout (flat, 16808 elements)
#define OFF_IDX  0
#define OFF_SCR  2400
#define OFF_BOX  4800
#define OFF_CLS  14400
#define OFF_NDT  16800

// IoU > thr test, matching reference arithmetic exactly (no FMA contraction).
__device__ __forceinline__ bool iou_gt(float c0, float c1, float c2, float c3,
                                       float t0, float t1, float t2, float t3,
                                       float tarea)
{
#pragma clang fp contract(off)
    float xx1 = fmaxf(c0, t0);
    float yy1 = fmaxf(c1, t1);
    float xx2 = fminf(c2, t2);
    float yy2 = fminf(c3, t3);
    float w = xx2 - xx1; w = fmaxf(w, 0.0f);
    float h = yy2 - yy1; h = fmaxf(h, 0.0f);
    float inter = w * h;
    float areac = (c2 - c0) * (c3 - c1);
    float uni = areac + tarea - inter;
    return (inter / uni) > 0.65f;
}

__device__ __forceinline__ uint64_t shfl_xor64(uint64_t x, int m)
{
    unsigned lo = __shfl_xor((unsigned)x, m, 64);
    unsigned hi = __shfl_xor((unsigned)(x >> 32), m, 64);
    return ((uint64_t)hi << 32) | lo;
}

__device__ __forceinline__ void ce64(uint64_t& a, uint64_t& b, bool desc)
{
    uint64_t lo = (a < b) ? a : b;
    uint64_t hi = (a < b) ? b : a;
    a = desc ? hi : lo;
    b = desc ? lo : hi;
}

// =================== one block per batch; zero inter-block traffic ===================
// 8 blocks x 768 threads (12 waves).
//   scan:    stage scores + validity-encoded class bytes into LDS; count per class.
//   binning: wave-0 prefix over 80 counts -> counting-sort scatter of element
//            indices into per-class LDS segments (ONE pass; replaces round-7's
//            80 per-wave full-array ballot scans — that was ~half the serial work).
//   NMS:     waves pull classes from an LDS work queue (load-balances medium-path
//            outliers): key build from segment -> in-wave bitonic (64/128) ->
//            LDS-staged IoU (block-broadcast form, no serial shfl chain) ->
//            serial-ballot suppress -> survivor bitmask + fused histogram.
//   select:  exact-bin cutoff -> gather <=512 candidates -> 256-thread x 4-elem
//            1024-key bitonic -> pack.
// No workspace, no fences, no global atomics, no memset dispatch.
__global__ __launch_bounds__(NTHR)
void k_nms_batch(const float* __restrict__ scores,
                 const float* __restrict__ boxes,
                 const int*   __restrict__ classes,
                 float* __restrict__ out)
{
    const int b    = blockIdx.x;
    const int tid  = threadIdx.x;
    const int lane = tid & 63;
    const int wv   = tid >> 6;           // 0..11
    const int bN   = b * NN;
    const uint64_t lmask = (1ull << lane) - 1ull;

    __shared__ alignas(16) float          score_s[NN];       // 16 KB
    __shared__ alignas(16) unsigned char  cls8[NN];          //  4 KB (0xFF = invalid)
    __shared__ alignas(16) unsigned short segi[NN];          //  8 KB class-sorted elem idx
    __shared__ int      cls_off[NCLS + 1];                   // exclusive offsets
    __shared__ int      ccnt[NCLS];                          // counts, then scatter cursors
    __shared__ alignas(16) float4 wbx_s[12 * 128];           // 24 KB per-wave box stage
    __shared__ float    war_s[12 * 128];                     //  6 KB per-wave areas
    __shared__ int      hist[256];                           //  1 KB
    __shared__ uint64_t cand[1024];                          //  8 KB
    __shared__ unsigned aliveE[NN / 32];                     //  0.5 KB survivor bitmask
    __shared__ int      keptn_s, ncand_s, cutoff_s, nextc_s;

    // ---- init + static output fills (out poisoned each replay) ----
    if (tid < NN / 32) aliveE[tid] = 0u;
    if (tid < 256) hist[tid] = 0;
    if (tid < NCLS) ccnt[tid] = 0;
    if (tid == 0) { keptn_s = 0; ncand_s = 0; cutoff_s = 256; nextc_s = 0; }
    if (tid < MAXDET) {
        out[OFF_IDX + b * MAXDET + tid] = -1.0f;
        out[OFF_SCR + b * MAXDET + tid] = 0.0f;
        int ob = OFF_BOX + (b * MAXDET + tid) * 4;
        out[ob + 0] = 0.0f; out[ob + 1] = 0.0f;
        out[ob + 2] = 0.0f; out[ob + 3] = 0.0f;
        out[OFF_CLS + b * MAXDET + tid] = 0.0f;
    }
    __syncthreads();

    // ---- scan: stage scores + class bytes, count valid per class ----
    {
        const float4* s4 = (const float4*)(scores + bN);
        const int4*   c4 = (const int4*)(classes + bN);
        for (int vi = tid; vi < NN / 4; vi += NTHR) {
            const float4 sv = s4[vi];
            const int4   cv = c4[vi];
            ((float4*)score_s)[vi] = sv;
            unsigned p0 = (sv.x > 0.05f) ? (unsigned)cv.x : 0xFFu;
            unsigned p1 = (sv.y > 0.05f) ? (unsigned)cv.y : 0xFFu;
            unsigned p2 = (sv.z > 0.05f) ? (unsigned)cv.z : 0xFFu;
            unsigned p3 = (sv.w > 0.05f) ? (unsigned)cv.w : 0xFFu;
            ((unsigned*)cls8)[vi] = p0 | (p1 << 8) | (p2 << 16) | (p3 << 24);
            if (p0 != 0xFFu) atomicAdd(&ccnt[p0], 1);
            if (p1 != 0xFFu) atomicAdd(&ccnt[p1], 1);
            if (p2 != 0xFFu) atomicAdd(&ccnt[p2], 1);
            if (p3 != 0xFFu) atomicAdd(&ccnt[p3], 1);
        }
    }
    __syncthreads();

    // ---- prefix over 80 counts (wave 0); reset ccnt to scatter cursors ----
    if (wv == 0) {
        const int n0 = ccnt[lane];
        const int n1 = (64 + lane < NCLS) ? ccnt[64 + lane] : 0;
        int x = n0;
#pragma unroll
        for (int off = 1; off < 64; off <<= 1) {
            int t = __shfl_up(x, off, 64);
            if (lane >= off) x += t;
        }
        const int total0 = __shfl(x, 63, 64);
        const int pre0 = x - n0;
        int y = n1;
#pragma unroll
        for (int off = 1; off < 64; off <<= 1) {
            int t = __shfl_up(y, off, 64);
            if (lane >= off) y += t;
        }
        const int total1 = __shfl(y, 63, 64);
        const int pre1 = total0 + y - n1;
        cls_off[lane] = pre0;
        ccnt[lane] = pre0;
        if (64 + lane < NCLS) { cls_off[64 + lane] = pre1; ccnt[64 + lane] = pre1; }
        if (lane == 0) cls_off[NCLS] = total0 + total1;
    }
    __syncthreads();

    // ---- counting-sort scatter: element indices into per-class segments ----
    for (int e = tid; e < NN; e += NTHR) {
        const unsigned c = cls8[e];
        if (c != 0xFFu) {
            int s = atomicAdd(&ccnt[c], 1);
            segi[s] = (unsigned short)e;
        }
    }
    __syncthreads();

    // ---- per-class NMS: dynamic work queue over 80 classes ----
    float4* wbx = &wbx_s[wv * 128];
    float*  war = &war_s[wv * 128];
    const float4* boxes4 = (const float4*)boxes;

    for (;;) {
        int q = 0;
        if (lane == 0) q = atomicAdd(&nextc_s, 1);
        q = __shfl(q, 0, 64);
        if (q >= NCLS) break;
        const int sbase = cls_off[q];
        const int ncf = cls_off[q + 1] - sbase;
        const int nc = ncf > 128 ? 128 : ncf;
        if (nc <= 0) continue;

        if (nc <= 64) {
            // ---- fast path: in-wave descending bitonic of 64 keys ----
            uint64_t key = 0ull;
            if (lane < nc) {
                const unsigned e = segi[sbase + lane];
                const unsigned sb = __float_as_uint(score_s[e]) | 0x80000000u;
                key = ((uint64_t)sb << 32) | e;
            }
            for (int k = 2; k <= 64; k <<= 1) {
                bool up = ((lane & k) == 0);
                for (int j = k >> 1; j >= 1; j >>= 1) {
                    uint64_t w = shfl_xor64(key, j);
                    bool km = (((lane & j) == 0) == up);
                    key = km ? (key > w ? key : w) : (key < w ? key : w);
                }
            }
            const unsigned idx = (unsigned)key;
            float4 bx = make_float4(0, 0, 0, 0);
            float  area = 0.0f;
            if (lane < nc) {
                bx = boxes4[bN + idx];
                {
#pragma clang fp contract(off)
                    area = (bx.z - bx.x) * (bx.w - bx.y);
                }
            }
            wbx[lane] = bx;
            war[lane] = area;
            uint64_t ov = 0;
            for (int j0 = 0; j0 < nc - 1; j0 += 4) {
                float4 t[4]; float ta[4];
#pragma unroll
                for (int r = 0; r < 4; ++r) { t[r] = wbx[j0 + r]; ta[r] = war[j0 + r]; }
#pragma unroll
                for (int r = 0; r < 4; ++r) {
                    int j = j0 + r;
                    if (j < nc - 1 && lane > j && lane < nc &&
                        iou_gt(bx.x, bx.y, bx.z, bx.w,
                               t[r].x, t[r].y, t[r].z, t[r].w, ta[r]))
                        ov |= 1ull << j;
                }
            }
            uint64_t alive = (nc >= 64) ? ~0ull : ((1ull << nc) - 1ull);
            for (int t = 0; t < nc; ++t) {
                if (!((alive >> t) & 1ull)) continue;
                uint64_t die = __ballot(((ov >> t) & 1ull) != 0);
                alive &= ~die;
            }
            if (lane == 0) atomicAdd(&keptn_s, __popcll(alive));
            if (lane < nc && ((alive >> lane) & 1ull)) {
                atomicOr(&aliveE[idx >> 5], 1u << (idx & 31));
                float f = __uint_as_float((unsigned)(key >> 32) & 0x7FFFFFFFu);
                int bin = (int)(f * 256.0f); bin = bin > 255 ? 255 : bin;
                atomicAdd(&hist[bin], 1);
            }
        } else {
            // ---- medium path (rare, nc in 65..128): 2-reg bitonic + LDS-staged IoU ----
            const int mB = 64 + lane;
            uint64_t kA = 0ull, kB = 0ull;
            if (lane < nc) {
                const unsigned e = segi[sbase + lane];
                kA = (((uint64_t)(__float_as_uint(score_s[e]) | 0x80000000u)) << 32) | e;
            }
            if (mB < nc) {
                const unsigned e = segi[sbase + mB];
                kB = (((uint64_t)(__float_as_uint(score_s[e]) | 0x80000000u)) << 32) | e;
            }
            for (int k = 2; k <= 128; k <<= 1) {
                bool up0 = ((lane & k) == 0);
                bool up1 = ((mB & k) == 0);
                for (int j = k >> 1; j >= 1; j >>= 1) {
                    if (j == 64) {
                        ce64(kA, kB, up0);   // k==128 here: up0 == true
                    } else {
                        uint64_t wA = shfl_xor64(kA, j);
                        uint64_t wB = shfl_xor64(kB, j);
                        bool kmA = (((lane & j) == 0) == up0);
                        bool kmB = (((lane & j) == 0) == up1);
                        kA = kmA ? (kA > wA ? kA : wA) : (kA < wA ? kA : wA);
                        kB = kmB ? (kB > wB ? kB : wB) : (kB < wB ? kB : wB);
                    }
                }
            }
            const unsigned idxA = (unsigned)kA, idxB = (unsigned)kB;
            float4 bA = make_float4(0, 0, 0, 0), bB = bA;
            float  aA = 0.0f, aB = 0.0f;
            if (lane < nc) {
                bA = boxes4[bN + idxA];
                {
#pragma clang fp contract(off)
                    aA = (bA.z - bA.x) * (bA.w - bA.y);
                }
            }
            if (mB < nc) {
                bB = boxes4[bN + idxB];
                {
#pragma clang fp contract(off)
                    aB = (bB.z - bB.x) * (bB.w - bB.y);
                }
            }
            wbx[lane] = bA;      war[lane] = aA;
            wbx[64 + lane] = bB; war[64 + lane] = aB;
            uint64_t ovA0 = 0, ovB0 = 0, ovB1 = 0;
            for (int j0 = 0; j0 < nc - 1; j0 += 4) {
                float4 t[4]; float ta[4];
#pragma unroll
                for (int r = 0; r < 4; ++r) { t[r] = wbx[j0 + r]; ta[r] = war[j0 + r]; }
#pragma unroll
                for (int r = 0; r < 4; ++r) {
                    int j = j0 + r;
                    if (j >= nc - 1) continue;
                    if (j < 64) {
                        if (lane > j && lane < nc &&
                            iou_gt(bA.x, bA.y, bA.z, bA.w, t[r].x, t[r].y, t[r].z, t[r].w, ta[r]))
                            ovA0 |= 1ull << j;
                        if (mB < nc &&
                            iou_gt(bB.x, bB.y, bB.z, bB.w, t[r].x, t[r].y, t[r].z, t[r].w, ta[r]))
                            ovB0 |= 1ull << j;
                    } else {
                        if (mB > j && mB < nc &&
                            iou_gt(bB.x, bB.y, bB.z, bB.w, t[r].x, t[r].y, t[r].z, t[r].w, ta[r]))
                            ovB1 |= 1ull << (j - 64);
                    }
                }
            }
            uint64_t alive0 = (nc >= 64) ? ~0ull : ((1ull << nc) - 1ull);
            uint64_t alive1 = (nc >= 128) ? ~0ull : ((1ull << (nc - 64)) - 1ull);
            for (int t = 0; t < nc; ++t) {
                if (t < 64) {
                    if (!((alive0 >> t) & 1ull)) continue;
                    uint64_t d0 = __ballot(((ovA0 >> t) & 1ull) != 0);
                    uint64_t d1 = __ballot(((ovB0 >> t) & 1ull) != 0);
                    alive0 &= ~d0;
                    alive1 &= ~d1;
                } else {
                    int tt = t - 64;
                    if (!((alive1 >> tt) & 1ull)) continue;
                    uint64_t d1 = __ballot(((ovB1 >> tt) & 1ull) != 0);
                    alive1 &= ~d1;
                }
            }
            if (lane == 0) atomicAdd(&keptn_s, __popcll(alive0) + __popcll(alive1));
            if (lane < nc && ((alive0 >> lane) & 1ull)) {
                atomicOr(&aliveE[idxA >> 5], 1u << (idxA & 31));
                float f = __uint_as_float((unsigned)(kA >> 32) & 0x7FFFFFFFu);
                int bin = (int)(f * 256.0f); bin = bin > 255 ? 255 : bin;
                atomicAdd(&hist[bin], 1);
            }
            if (mB < nc && ((alive1 >> lane) & 1ull)) {
                atomicOr(&aliveE[idxB >> 5], 1u << (idxB & 31));
                float f = __uint_as_float((unsigned)(kB >> 32) & 0x7FFFFFFFu);
                int bin = (int)(f * 256.0f); bin = bin > 255 ? 255 : bin;
                atomicAdd(&hist[bin], 1);
            }
        }
    }
    __syncthreads();

    // ---- cutoff: exact 1-bin granularity (wave 0) ----
    const int kept_n = keptn_s;
    const int target = kept_n < MAXDET ? kept_n : MAXDET;
    if (tid == 0) out[OFF_NDT + b] = (float)target;
    if (wv == 0) {
        int h0 = hist[4 * lane + 0], h1 = hist[4 * lane + 1];
        int h2 = hist[4 * lane + 2], h3 = hist[4 * lane + 3];
        int s = h0 + h1 + h2 + h3;
#pragma unroll
        for (int off = 1; off < 64; off <<= 1) {
            int t = __shfl_down(s, off, 64);
            if (lane + off < 64) s += t;
        }
        int snext = __shfl_down(s, 1, 64);
        if (lane == 63) snext = 0;
        int u0 = s;            // suffix(4L)
        int u1 = u0 - h0;      // suffix(4L+1)
        int u2 = u1 - h1;      // suffix(4L+2)
        int u3 = u2 - h2;      // suffix(4L+3)
        int u4 = snext;        // suffix(4L+4)
        if (target > 0) {
            if (u0 >= target && u1 < target) cutoff_s = 4 * lane + 0;
            if (u1 >= target && u2 < target) cutoff_s = 4 * lane + 1;
            if (u2 >= target && u3 < target) cutoff_s = 4 * lane + 2;
            if (u3 >= target && u4 < target) cutoff_s = 4 * lane + 3;
        }
    }
    __syncthreads();
    const int cutoff = cutoff_s;

    // ---- gather candidates from survivor bitmask ----
    for (int e = tid; e < NN; e += NTHR) {
        if ((aliveE[e >> 5] >> (e & 31)) & 1u) {
            float f = score_s[e];
            int bin = (int)(f * 256.0f); bin = bin > 255 ? 255 : bin;
            if (bin >= cutoff) {
                int slot = atomicAdd(&ncand_s, 1);
                if (slot < 512)
                    cand[slot] = (((uint64_t)(__float_as_uint(f) | 0x80000000u)) << 32) | (unsigned)e;
            }
        }
    }
    __syncthreads();
    const int ncand = ncand_s < 512 ? ncand_s : 512;
    for (int i = tid; i < 1024; i += NTHR)
        if (i >= ncand) cand[i] = 0ull;      // zero-pad slots ncand..1023
    __syncthreads();

    // ---- descending bitonic sort of 1024 u64 keys (256 thr x 4 elems) ----
    // Threads 256..767 idle but execute the barriers (compile-time loop bounds
    // -> block-uniform control flow).
    // i bits: [1:0]=e (register), [7:2]=lane (shfl), [9:8]=wave (LDS)
    const int base = tid << 2;
    uint64_t v[4] = {0ull, 0ull, 0ull, 0ull};
    if (tid < 256) {
#pragma unroll
        for (int e = 0; e < 4; ++e) v[e] = cand[base + e];
    }
    for (int k = 2; k <= 1024; k <<= 1) {
        for (int j = k >> 1; j >= 1; j >>= 1) {
            if (j >= 256) {
                __syncthreads();
                if (tid < 256) {
#pragma unroll
                    for (int e = 0; e < 4; ++e) cand[base + e] = v[e];
                }
                __syncthreads();
                if (tid < 256) {
                    const int pb = base ^ j;
                    const bool keepmax = (((base & j) == 0) == ((base & k) == 0));
                    uint64_t w[4];
#pragma unroll
                    for (int e = 0; e < 4; ++e) w[e] = cand[pb + e];
#pragma unroll
                    for (int e = 0; e < 4; ++e) {
                        uint64_t a = v[e], cc = w[e];
                        v[e] = keepmax ? (a > cc ? a : cc) : (a < cc ? a : cc);
                    }
                }
            } else if (j >= 4) {
                if (tid < 256) {
                    const int m = j >> 2;
                    const bool keepmax = (((lane & m) == 0) == ((base & k) == 0));
                    unsigned wlo[4], whi[4];
#pragma unroll
                    for (int e = 0; e < 4; ++e) wlo[e] = __shfl_xor((unsigned)v[e], m, 64);
#pragma unroll
                    for (int e = 0; e < 4; ++e) whi[e] = __shfl_xor((unsigned)(v[e] >> 32), m, 64);
#pragma unroll
                    for (int e = 0; e < 4; ++e) {
                        uint64_t w = ((uint64_t)whi[e] << 32) | wlo[e];
                        uint64_t a = v[e];
                        v[e] = keepmax ? (a > w ? a : w) : (a < w ? a : w);
                    }
                }
            } else if (j == 2) {
                if (tid < 256) {
                    bool d = ((base & k) == 0);
                    ce64(v[0], v[2], d);
                    ce64(v[1], v[3], d);
                }
            } else {
                if (tid < 256) {
                    bool d0 = (((base + 0) & k) == 0);
                    bool d2 = (((base + 2) & k) == 0);
                    ce64(v[0], v[1], d0);
                    ce64(v[2], v[3], d2);
                }
            }
        }
    }

    // ---- pack top-target detections (rank = sorted position) ----
    if (tid < 256) {
#pragma unroll
        for (int e = 0; e < 4; ++e) {
            const int rank = base + e;
            if (rank < target) {
                const uint64_t kv = v[e];
                const unsigned idx = (unsigned)kv;
                out[OFF_SCR + b * MAXDET + rank] = __uint_as_float((unsigned)(kv >> 32) & 0x7FFFFFFFu);
                float4 g = boxes4[bN + idx];
                int ob = OFF_BOX + (b * MAXDET + rank) * 4;
                out[ob + 0] = g.x; out[ob + 1] = g.y;
                out[ob + 2] = g.z; out[ob + 3] = g.w;
                out[OFF_CLS + b * MAXDET + rank] = (float)cls8[idx];
            }
        }
    }
}

extern "C" void kernel_launch(void* const* d_in, const int* in_sizes, int n_in,
                              void* d_out, int out_size, void* d_ws, size_t ws_size,
                              hipStream_t stream)
{
    const float* scores  = (const float*)d_in[0];
    const float* boxes   = (const float*)d_in[1];
    const int*   classes = (const int*)d_in[2];
    float*       out     = (float*)d_out;

    hipLaunchKernelGGL(k_nms_batch, dim3(NB), dim3(NTHR), 0, stream,
                       scores, boxes, classes, out);
}